// Round 15
// baseline (104.022 us; speedup 1.0000x reference)
//
#include <hip/hip_runtime.h>
#include <hip/hip_bf16.h>

typedef __attribute__((ext_vector_type(8))) __bf16 bf16x8;
typedef __attribute__((ext_vector_type(4))) float f32x4;
typedef __attribute__((ext_vector_type(16))) float f32x16;

union U8 { bf16x8 v; unsigned u[4]; uint2 d[2]; };

#define ALPHA 0.999f
#define THETA 0.05f

#define K1_BLOCKS 1024
#define K3_BLOCKS 1024

// k1: 32-row per-wave region. Row stride 100 halfs (50 dwords, gcd=2 -> free).
// Fields: dy@0(16) | h@16(32) | q@48(16) | dh@64(32).
#define RREC 100
#define F_DY 0
#define F_H  16
#define F_Q  48
#define F_DH 64
#define WAVE_HALFS (32*RREC)              // 6.4 KB / wave
#define K1_SMEM_BYTES 51200               // 8 waves * 6.4KB (>= 28672 reduction)

// k3 per-row record: qhi@0(16) | qlo@16(16) | hhi@32(32) | hlo@64(32)
#define R3 100
#define Q_HI 0
#define Q_LO 16
#define H_HI 32
#define H_LO 64

#if __has_builtin(__builtin_amdgcn_rcpf)
#define RCPF(x) __builtin_amdgcn_rcpf(x)
#else
#define RCPF(x) (1.f/(x))
#endif
#if __has_builtin(__builtin_amdgcn_rsqf)
#define RSQF(x) __builtin_amdgcn_rsqf(x)
#else
#define RSQF(x) (1.f/sqrtf(x))
#endif

__device__ __forceinline__ float sigmoidf_(float z){ return RCPF(1.f + __expf(-z)); }

__device__ __forceinline__ unsigned pk2_(float a, float b){
  union { __bf16 h[2]; unsigned u; } x; x.h[0]=(__bf16)a; x.h[1]=(__bf16)b; return x.u;
}
__device__ __forceinline__ float upks_(unsigned u, int s){
  return s ? __uint_as_float(u & 0xffff0000u) : __uint_as_float(u << 16);
}
__device__ __forceinline__ void splitpk_(float a, float b, unsigned &uh, unsigned &ul){
  unsigned h = pk2_(a,b);
  float ah = __uint_as_float(h << 16);
  float bh = __uint_as_float(h & 0xffff0000u);
  uh = h; ul = pk2_(a - ah, b - bh);
}
__device__ __forceinline__ void load_split8_(const float* p, U8 &H, U8 &L){
  const float4 u0 = *(const float4*)p;
  const float4 u1 = *(const float4*)(p+4);
  splitpk_(u0.x,u0.y,H.u[0],L.u[0]); splitpk_(u0.z,u0.w,H.u[1],L.u[1]);
  splitpk_(u1.x,u1.y,H.u[2],L.u[2]); splitpk_(u1.z,u1.w,H.u[3],L.u[3]);
}
__device__ __forceinline__ void pack8f_(const float* p, U8 &A){
  const float4 u0 = *(const float4*)p;
  const float4 u1 = *(const float4*)(p+4);
  A.u[0]=pk2_(u0.x,u0.y); A.u[1]=pk2_(u0.z,u0.w); A.u[2]=pk2_(u1.x,u1.y); A.u[3]=pk2_(u1.z,u1.w);
}

// ---------------- Kernel 1: gradient pass ----------------
// (512,2): per the R1-R14 law, min=2 => VGPR cap ~124 (fits this ~90-reg body,
// no spill) while a 512-thread block = 8 waves => 2 resident blocks = 16
// waves/CU (50%) -- strictly better than (256,3)'s 84-cap/12-wave tier.
// Wave-level body identical to R13's proven 55us kernel.
__global__ __launch_bounds__(512, 2)
void k1_grad(const float* __restrict__ X,
             const float* __restrict__ W0, const float* __restrict__ b0,
             const float* __restrict__ W1, const float* __restrict__ b1,
             const float* __restrict__ WV, const float* __restrict__ WQ,
             float* __restrict__ wsPart, int N)
{
  __shared__ __align__(16) unsigned char smem_raw[K1_SMEM_BYTES];
  const int tid = threadIdx.x;
  const int w = tid >> 6, l = tid & 63;
  const int row = l & 31, hi = l >> 5;
  const int c16 = l & 15, g16 = l >> 4;
  __bf16* WB = (__bf16*)smem_raw + w*WAVE_HALFS;

  bf16x8 ones;
  #pragma unroll
  for (int i=0;i<8;++i) ones[i] = (__bf16)1.f;

  U8 aWVQ, aW0p;
  pack8f_((row < 16) ? (WV + row*16 + hi*8) : (WQ + (row-16)*16 + hi*8), aWVQ);
  pack8f_(W0 + row*16 + hi*8, aW0p);

  f32x4 accW[4] = {};
  f32x4 accB1 = {}, accB0a = {}, accB0b = {};

  const int nb = N >> 6;
  const int tw = K1_BLOCKS*8;
  const int gw = blockIdx.x*8 + w;
  const int iters = (nb + tw - 1) / tw;

  for (int it = 0; it < iters; ++it) {
    const int batch = gw + it*tw;
    if (batch < nb) {
      const float* xb = X + (size_t)batch*1024;

      #pragma unroll
      for (int hf=0; hf<2; ++hf){
        const float* xh = xb + hf*512;
        __bf16* R = WB + row*RREC;

        // ---- phase 1: one MFMA -> v (rows 0-15) and q-pre (rows 16-31) ----
        U8 bX; pack8f_(xh + row*16 + hi*8, bX);
        f32x16 c1;
        #pragma unroll
        for (int i=0;i<16;++i) c1[i] = 0.f;
        c1 = __builtin_amdgcn_mfma_f32_32x32x16_bf16(aWVQ.v, bX.v, c1, 0,0,0);
        unsigned vvp[4];
        #pragma unroll
        for (int j=0;j<4;++j){
          float a = c1[2*j],  sa = a*sigmoidf_(a);
          float b = c1[2*j+1],sb = b*sigmoidf_(b);
          vvp[j] = pk2_(sa, sb);
        }
        float qv[8]; float n2 = 0.f;
        #pragma unroll
        for (int r=0;r<8;++r){
          float s = c1[8+r]; float t = s*sigmoidf_(s);
          qv[r] = t; n2 = fmaf(t,t,n2);
        }
        n2 += __shfl_xor(n2, 32);
        const float inv = RSQF(fmaxf(n2, 1e-24f));
        *(uint2*)(R + F_Q + 4*hi)     = make_uint2(pk2_(qv[0]*inv,qv[1]*inv), pk2_(qv[2]*inv,qv[3]*inv));
        *(uint2*)(R + F_Q + 8 + 4*hi) = make_uint2(pk2_(qv[4]*inv,qv[5]*inv), pk2_(qv[6]*inv,qv[7]*inv));

        // ---- phase 2: h = silu(W0 q^T + b0), one MFMA ----
        U8 bq;
        { const __bf16* p = R + F_Q + hi*8;
          bq.d[0] = *(const uint2*)p; bq.d[1] = *(const uint2*)(p+4); }
        f32x16 c2;
        { const float4 bA = *(const float4*)(b0 + 4*hi);
          const float4 bB = *(const float4*)(b0 + 8 + 4*hi);
          const float4 bC = *(const float4*)(b0 + 16 + 4*hi);
          const float4 bD = *(const float4*)(b0 + 24 + 4*hi);
          c2[0]=bA.x;c2[1]=bA.y;c2[2]=bA.z;c2[3]=bA.w;
          c2[4]=bB.x;c2[5]=bB.y;c2[6]=bB.z;c2[7]=bB.w;
          c2[8]=bC.x;c2[9]=bC.y;c2[10]=bC.z;c2[11]=bC.w;
          c2[12]=bD.x;c2[13]=bD.y;c2[14]=bD.z;c2[15]=bD.w; }
        c2 = __builtin_amdgcn_mfma_f32_32x32x16_bf16(aW0p.v, bq.v, c2, 0,0,0);
        unsigned hpk[8], dshp[8];
        #pragma unroll
        for (int j=0;j<8;++j){
          float sa = c2[2*j],   sga = sigmoidf_(sa);
          float sb = c2[2*j+1], sgb = sigmoidf_(sb);
          hpk[j]  = pk2_(sa*sga, sb*sgb);
          dshp[j] = pk2_(sga*fmaf(sa,1.f-sga,1.f), sgb*fmaf(sb,1.f-sgb,1.f));
        }
        *(uint2*)(R + F_H + 4*hi)      = make_uint2(hpk[0],hpk[1]);
        *(uint2*)(R + F_H + 8 + 4*hi)  = make_uint2(hpk[2],hpk[3]);
        *(uint2*)(R + F_H + 16 + 4*hi) = make_uint2(hpk[4],hpk[5]);
        *(uint2*)(R + F_H + 24 + 4*hi) = make_uint2(hpk[6],hpk[7]);

        // ---- phase 3: y = silu(W1 h^T + b1); dy -> F_DY ----
        U8 a1, a2;
        #pragma unroll
        for (int i=0;i<4;++i){ a1.u[i]=0; a2.u[i]=0; }
        if (row < 16) pack8f_(W1 + row*32 + hi*8, a1);
        else          pack8f_(W1 + (row-16)*32 + 16 + hi*8, a2);
        U8 bhlo, bhhi;
        { const __bf16* p = R + F_H + hi*8;
          bhlo.d[0] = *(const uint2*)p; bhlo.d[1] = *(const uint2*)(p+4);
          const __bf16* p2 = R + F_H + 16 + hi*8;
          bhhi.d[0] = *(const uint2*)p2; bhhi.d[1] = *(const uint2*)(p2+4); }
        f32x16 c3;
        { const float4 bA = *(const float4*)(b1 + 4*hi);
          const float4 bB = *(const float4*)(b1 + 8 + 4*hi);
          c3[0]=bA.x;c3[1]=bA.y;c3[2]=bA.z;c3[3]=bA.w;
          c3[4]=bB.x;c3[5]=bB.y;c3[6]=bB.z;c3[7]=bB.w;
          #pragma unroll
          for (int i=8;i<16;++i) c3[i]=0.f; }
        c3 = __builtin_amdgcn_mfma_f32_32x32x16_bf16(a1.v, bhlo.v, c3, 0,0,0);
        c3 = __builtin_amdgcn_mfma_f32_32x32x16_bf16(a2.v, bhhi.v, c3, 0,0,0);
        unsigned dypk[4];
        #pragma unroll
        for (int j=0;j<4;++j){
          float d2[2];
          #pragma unroll
          for (int e=0;e<2;++e){
            int r = 2*j+e;
            float s = c3[r] + c3[r+8];
            float sg = sigmoidf_(s);
            float y = s*sg;
            float ds = sg * fmaf(s, 1.f - sg, 1.f);
            d2[e] = (y - upks_(vvp[r>>1], r&1)) * ds;
          }
          dypk[j] = pk2_(d2[0], d2[1]);
        }
        *(uint2*)(R + F_DY + 4*hi)     = make_uint2(dypk[0],dypk[1]);
        *(uint2*)(R + F_DY + 8 + 4*hi) = make_uint2(dypk[2],dypk[3]);

        // ---- phase 4: dh = (W1^T dy^T) * dsilu -> F_DH, one MFMA ----
        U8 aT;
        { float t0 = W1[(hi*8+0)*32 + row], t1 = W1[(hi*8+1)*32 + row];
          float t2 = W1[(hi*8+2)*32 + row], t3 = W1[(hi*8+3)*32 + row];
          float t4 = W1[(hi*8+4)*32 + row], t5 = W1[(hi*8+5)*32 + row];
          float t6 = W1[(hi*8+6)*32 + row], t7 = W1[(hi*8+7)*32 + row];
          aT.u[0]=pk2_(t0,t1); aT.u[1]=pk2_(t2,t3); aT.u[2]=pk2_(t4,t5); aT.u[3]=pk2_(t6,t7); }
        U8 bdy;
        { const __bf16* p = R + F_DY + hi*8;
          bdy.d[0] = *(const uint2*)p; bdy.d[1] = *(const uint2*)(p+4); }
        f32x16 c4;
        #pragma unroll
        for (int i=0;i<16;++i) c4[i]=0.f;
        c4 = __builtin_amdgcn_mfma_f32_32x32x16_bf16(aT.v, bdy.v, c4, 0,0,0);
        unsigned dhpk[8];
        #pragma unroll
        for (int j=0;j<8;++j){
          float d0 = c4[2*j]   * upks_(dshp[j],0);
          float d1 = c4[2*j+1] * upks_(dshp[j],1);
          dhpk[j] = pk2_(d0,d1);
        }
        *(uint2*)(R + F_DH + 4*hi)      = make_uint2(dhpk[0],dhpk[1]);
        *(uint2*)(R + F_DH + 8 + 4*hi)  = make_uint2(dhpk[2],dhpk[3]);
        *(uint2*)(R + F_DH + 16 + 4*hi) = make_uint2(dhpk[4],dhpk[5]);
        *(uint2*)(R + F_DH + 24 + 4*hi) = make_uint2(dhpk[6],dhpk[7]);

        // ---- gradient MFMAs (16x16x32, proven path) ----
        const __bf16* gbase = WB + (g16*8)*RREC + c16;
        {
          bf16x8 fdy, fh0, fh1;
          #pragma unroll
          for (int i=0;i<8;++i){
            const __bf16* pr = gbase + i*RREC;
            fdy[i] = pr[F_DY];
            fh0[i] = pr[F_H];
            fh1[i] = pr[F_H + 16];
          }
          accW[0] = __builtin_amdgcn_mfma_f32_16x16x32_bf16(fdy, fh0, accW[0], 0,0,0);
          accW[1] = __builtin_amdgcn_mfma_f32_16x16x32_bf16(fdy, fh1, accW[1], 0,0,0);
          accB1   = __builtin_amdgcn_mfma_f32_16x16x32_bf16(fdy, ones, accB1, 0,0,0);
        }
        {
          bf16x8 fd0, fd1, fq;
          #pragma unroll
          for (int i=0;i<8;++i){
            const __bf16* pr = gbase + i*RREC;
            fd0[i] = pr[F_DH];
            fd1[i] = pr[F_DH + 16];
            fq[i]  = pr[F_Q];
          }
          accW[2] = __builtin_amdgcn_mfma_f32_16x16x32_bf16(fd0, fq, accW[2], 0,0,0);
          accW[3] = __builtin_amdgcn_mfma_f32_16x16x32_bf16(fd1, fq, accW[3], 0,0,0);
          accB0a  = __builtin_amdgcn_mfma_f32_16x16x32_bf16(fd0, ones, accB0a, 0,0,0);
          accB0b  = __builtin_amdgcn_mfma_f32_16x16x32_bf16(fd1, ones, accB0b, 0,0,0);
        }
      }
    }
  }

  // ---- block reduction over 8 waves (two-stage into 4 x 1792 floats) ----
  __syncthreads();
  float* red = (float*)smem_raw;
  if (w < 4){
    #pragma unroll
    for (int r=0;r<4;++r){
      red[w*1792 + 0*256 + l*4 + r] = accW[0][r];
      red[w*1792 + 1*256 + l*4 + r] = accW[1][r];
      red[w*1792 + 2*256 + l*4 + r] = accB1[r];
      red[w*1792 + 3*256 + l*4 + r] = accW[2][r];
      red[w*1792 + 4*256 + l*4 + r] = accW[3][r];
      red[w*1792 + 5*256 + l*4 + r] = accB0a[r];
      red[w*1792 + 6*256 + l*4 + r] = accB0b[r];
    }
  }
  __syncthreads();
  if (w >= 4){
    const int wb = (w-4)*1792;
    #pragma unroll
    for (int r=0;r<4;++r){
      red[wb + 0*256 + l*4 + r] += accW[0][r];
      red[wb + 1*256 + l*4 + r] += accW[1][r];
      red[wb + 2*256 + l*4 + r] += accB1[r];
      red[wb + 3*256 + l*4 + r] += accW[2][r];
      red[wb + 4*256 + l*4 + r] += accW[3][r];
      red[wb + 5*256 + l*4 + r] += accB0a[r];
      red[wb + 6*256 + l*4 + r] += accB0b[r];
    }
  }
  __syncthreads();
  for (int s = tid; s < 1792; s += 512){
    float sum = red[s] + red[1792+s] + red[2*1792+s] + red[3*1792+s];
    wsPart[(size_t)blockIdx.x*1792 + s] = sum;
  }
}

// ---------------- Kernel 2a: partial reduce (1024 -> 16 chunks) ----------------
__global__ void k2a_reduce(const float* __restrict__ wsPart, float* __restrict__ tmp)
{
  const int s = blockIdx.x*256 + threadIdx.x;
  const int c = blockIdx.y;
  float g = 0.f;
  #pragma unroll 8
  for (int j=0;j<64;++j) g += wsPart[(size_t)(c*64+j)*1792 + s];
  tmp[(size_t)c*1792 + s] = g;
}

// ---------------- Kernel 2b: final reduce, form updated params ----------------
__global__ void k2b_reduce(const float* __restrict__ tmp,
                           const float* __restrict__ W0, const float* __restrict__ b0,
                           const float* __restrict__ W1, const float* __restrict__ b1,
                           float* __restrict__ P, float scale)
{
  int s = blockIdx.x*256 + threadIdx.x;
  if (s >= 1792) return;
  float g = 0.f;
  #pragma unroll
  for (int c=0;c<16;++c) g += tmp[(size_t)c*1792 + s];
  g *= scale;
  int a = s >> 8, l = (s >> 2) & 63, r = s & 3;
  int m = ((l>>4)<<2) + r, n = l & 15;
  if (a==0)      P[544 + m*32 + n]       = ALPHA*W1[m*32+n]        - THETA*g;
  else if (a==1) P[544 + m*32 + 16 + n]  = ALPHA*W1[m*32+16+n]     - THETA*g;
  else if (a==2){ if (n==0) P[1056 + m]  = ALPHA*b1[m]             - THETA*g; }
  else if (a==3) P[m*16 + n]             = ALPHA*W0[m*16+n]        - THETA*g;
  else if (a==4) P[(16+m)*16 + n]        = ALPHA*W0[(16+m)*16+n]   - THETA*g;
  else if (a==5){ if (n==0) P[512 + m]   = ALPHA*b0[m]             - THETA*g; }
  else           { if (n==0) P[512+16+m] = ALPHA*b0[16+m]          - THETA*g; }
}

// ---------------- Kernel 3: retrieve, 32x32x16 MFMA with [Wh;Wl] A-packing ----------------
__global__ __launch_bounds__(512, 2)
void k3_retrieve(const float* __restrict__ X, const float* __restrict__ WQ,
                 const float* __restrict__ P, float* __restrict__ out, int N)
{
  __shared__ __align__(16) __bf16 smem[8*32*R3];   // 51200 B
  const int tid = threadIdx.x;
  const int w = tid >> 6, l = tid & 63;
  const int col = l & 31, hi = l >> 5;
  __bf16* WB = smem + w*32*R3;
  __bf16* R = WB + col*R3;

  // A-frags
  U8 aQ, aW0h_, aW0l_, a1, a2;
  {
    U8 Hh, Ll;
    load_split8_(WQ + (col & 15)*16 + hi*8, Hh, Ll);
    aQ = (col < 16) ? Hh : Ll;                       // [WQh; WQl]
    load_split8_(P + col*16 + hi*8, aW0h_, aW0l_);   // W0' 32 rows native
    load_split8_(P + 544 + (col & 15)*32 + hi*8, Hh, Ll);
    a1 = (col < 16) ? Hh : Ll;                       // [W1h; W1l], k 0-15
    load_split8_(P + 544 + (col & 15)*32 + 16 + hi*8, Hh, Ll);
    a2 = (col < 16) ? Hh : Ll;                       // [W1h; W1l], k 16-31
  }

  const int nb = N >> 6;
  const int tw = K3_BLOCKS*8;
  const int gw = blockIdx.x*8 + w;
  const int iters = (nb + tw - 1) / tw;

  for (int it=0; it<iters; ++it){
    const int batch = gw + it*tw;
    if (batch < nb){
      #pragma unroll
      for (int sb=0; sb<2; ++sb){
        const float* xs = X + (size_t)batch*1024 + sb*512;

        // ---- phase 1: s = WQ x^T (exact); q = silu(l2norm(s)) hi/lo -> LDS ----
        U8 bXh, bXl;
        load_split8_(xs + col*16 + hi*8, bXh, bXl);
        f32x16 c1;
        #pragma unroll
        for (int i=0;i<16;++i) c1[i]=0.f;
        c1 = __builtin_amdgcn_mfma_f32_32x32x16_bf16(aQ.v, bXh.v, c1, 0,0,0);
        c1 = __builtin_amdgcn_mfma_f32_32x32x16_bf16(aQ.v, bXl.v, c1, 0,0,0);
        float sv[8]; float n2 = 0.f;
        #pragma unroll
        for (int r=0;r<8;++r){ sv[r] = c1[r] + c1[r+8]; n2 = fmaf(sv[r],sv[r],n2); }
        n2 += __shfl_xor(n2, 32);
        const float inv = RSQF(fmaxf(n2, 1e-24f));
        unsigned qh[4], ql[4];
        #pragma unroll
        for (int j=0;j<4;++j){
          float z0 = sv[2*j]*inv,   z1 = sv[2*j+1]*inv;
          float q0 = z0*sigmoidf_(z0), q1 = z1*sigmoidf_(z1);
          splitpk_(q0,q1,qh[j],ql[j]);
        }
        *(uint2*)(R + Q_HI + 4*hi)     = make_uint2(qh[0],qh[1]);
        *(uint2*)(R + Q_HI + 8 + 4*hi) = make_uint2(qh[2],qh[3]);
        *(uint2*)(R + Q_LO + 4*hi)     = make_uint2(ql[0],ql[1]);
        *(uint2*)(R + Q_LO + 8 + 4*hi) = make_uint2(ql[2],ql[3]);

        // ---- phase 2: h = silu(W0' q^T + b0') hi/lo -> LDS ----
        U8 bqh, bql;
        { const __bf16* p = R + Q_HI + hi*8;
          bqh.d[0]=*(const uint2*)p; bqh.d[1]=*(const uint2*)(p+4);
          const __bf16* p2 = R + Q_LO + hi*8;
          bql.d[0]=*(const uint2*)p2; bql.d[1]=*(const uint2*)(p2+4); }
        f32x16 c2;
        { const float4 bA = *(const float4*)(P + 512 + 4*hi);
          const float4 bB = *(const float4*)(P + 512 + 8 + 4*hi);
          const float4 bC = *(const float4*)(P + 512 + 16 + 4*hi);
          const float4 bD = *(const float4*)(P + 512 + 24 + 4*hi);
          c2[0]=bA.x;c2[1]=bA.y;c2[2]=bA.z;c2[3]=bA.w;
          c2[4]=bB.x;c2[5]=bB.y;c2[6]=bB.z;c2[7]=bB.w;
          c2[8]=bC.x;c2[9]=bC.y;c2[10]=bC.z;c2[11]=bC.w;
          c2[12]=bD.x;c2[13]=bD.y;c2[14]=bD.z;c2[15]=bD.w; }
        c2 = __builtin_amdgcn_mfma_f32_32x32x16_bf16(aW0h_.v, bqh.v, c2, 0,0,0);
        c2 = __builtin_amdgcn_mfma_f32_32x32x16_bf16(aW0h_.v, bql.v, c2, 0,0,0);
        c2 = __builtin_amdgcn_mfma_f32_32x32x16_bf16(aW0l_.v, bqh.v, c2, 0,0,0);
        unsigned hh[8], hl[8];
        #pragma unroll
        for (int j=0;j<8;++j){
          float s0 = c2[2*j], s1 = c2[2*j+1];
          float h0 = s0*sigmoidf_(s0), h1 = s1*sigmoidf_(s1);
          splitpk_(h0,h1,hh[j],hl[j]);
        }
        *(uint2*)(R + H_HI + 4*hi)      = make_uint2(hh[0],hh[1]);
        *(uint2*)(R + H_HI + 8 + 4*hi)  = make_uint2(hh[2],hh[3]);
        *(uint2*)(R + H_HI + 16 + 4*hi) = make_uint2(hh[4],hh[5]);
        *(uint2*)(R + H_HI + 24 + 4*hi) = make_uint2(hh[6],hh[7]);
        *(uint2*)(R + H_LO + 4*hi)      = make_uint2(hl[0],hl[1]);
        *(uint2*)(R + H_LO + 8 + 4*hi)  = make_uint2(hl[2],hl[3]);
        *(uint2*)(R + H_LO + 16 + 4*hi) = make_uint2(hl[4],hl[5]);
        *(uint2*)(R + H_LO + 24 + 4*hi) = make_uint2(hl[6],hl[7]);

        // ---- phase 3: o = silu(W1' h^T + b1'), coalesced float4 writes ----
        U8 bhh0, bhh1, bhl0, bhl1;
        { const __bf16* p;
          p = R + H_HI + hi*8;      bhh0.d[0]=*(const uint2*)p; bhh0.d[1]=*(const uint2*)(p+4);
          p = R + H_HI + 16 + hi*8; bhh1.d[0]=*(const uint2*)p; bhh1.d[1]=*(const uint2*)(p+4);
          p = R + H_LO + hi*8;      bhl0.d[0]=*(const uint2*)p; bhl0.d[1]=*(const uint2*)(p+4);
          p = R + H_LO + 16 + hi*8; bhl1.d[0]=*(const uint2*)p; bhl1.d[1]=*(const uint2*)(p+4); }
        f32x16 c3;
        { const float4 bA = *(const float4*)(P + 1056 + 4*hi);
          const float4 bB = *(const float4*)(P + 1056 + 8 + 4*hi);
          c3[0]=bA.x;c3[1]=bA.y;c3[2]=bA.z;c3[3]=bA.w;
          c3[4]=bB.x;c3[5]=bB.y;c3[6]=bB.z;c3[7]=bB.w;
          #pragma unroll
          for (int i=8;i<16;++i) c3[i]=0.f; }
        c3 = __builtin_amdgcn_mfma_f32_32x32x16_bf16(a1.v, bhh0.v, c3, 0,0,0);
        c3 = __builtin_amdgcn_mfma_f32_32x32x16_bf16(a2.v, bhh1.v, c3, 0,0,0);
        c3 = __builtin_amdgcn_mfma_f32_32x32x16_bf16(a1.v, bhl0.v, c3, 0,0,0);
        c3 = __builtin_amdgcn_mfma_f32_32x32x16_bf16(a2.v, bhl1.v, c3, 0,0,0);
        float oo[8];
        #pragma unroll
        for (int r=0;r<8;++r){
          float s = c3[r] + c3[r+8];
          oo[r] = s * sigmoidf_(s);
        }
        const size_t xrow = (size_t)batch*64 + sb*32 + col;
        *(float4*)(out + xrow*16 + 4*hi)     = make_float4(oo[0],oo[1],oo[2],oo[3]);
        *(float4*)(out + xrow*16 + 8 + 4*hi) = make_float4(oo[4],oo[5],oo[6],oo[7]);
      }
    }
  }
}

extern "C" void kernel_launch(void* const* d_in, const int* in_sizes, int n_in,
                              void* d_out, int out_size, void* d_ws, size_t ws_size,
                              hipStream_t stream)
{
  const float* X  = (const float*)d_in[0];
  const float* W0 = (const float*)d_in[1];
  const float* b0 = (const float*)d_in[2];
  const float* W1 = (const float*)d_in[3];
  const float* b1 = (const float*)d_in[4];
  const float* WV = (const float*)d_in[6];
  const float* WQ = (const float*)d_in[7];
  float* ws   = (float*)d_ws;
  float* P    = ws;                         // 1072 floats of updated params
  float* part = ws + 2048;                  // 1024*1792 floats of partials
  float* tmp  = part + (size_t)K1_BLOCKS*1792;  // 16*1792 floats

  const int N = in_sizes[0] / 16;
  const float scale = 2.f / (16.f * (float)N);

  k1_grad<<<dim3(K1_BLOCKS), dim3(512), 0, stream>>>(X, W0, b0, W1, b1, WV, WQ, part, N);
  k2a_reduce<<<dim3(7,16), dim3(256), 0, stream>>>(part, tmp);
  k2b_reduce<<<dim3(7), dim3(256), 0, stream>>>(tmp, W0, b0, W1, b1, P, scale);
  k3_retrieve<<<dim3(K3_BLOCKS), dim3(512), 0, stream>>>(X, WQ, P, (float*)d_out, N);
}

// Round 16
// 89.916 us; speedup vs baseline: 1.1569x; 1.1569x over previous
//
#include <hip/hip_runtime.h>
#include <hip/hip_bf16.h>

typedef __attribute__((ext_vector_type(8))) __bf16 bf16x8;
typedef __attribute__((ext_vector_type(4))) float f32x4;
typedef __attribute__((ext_vector_type(16))) float f32x16;

union U8 { bf16x8 v; unsigned u[4]; uint2 d[2]; };

#define ALPHA 0.999f
#define THETA 0.05f

#define K1_BLOCKS 1536
#define K3_BLOCKS 1536

// k1: 32-row per-wave region. Row stride 100 halfs (50 dwords, gcd=2 -> free).
// Fields: dy@0(16) | h@16(32) | q@48(16) | dh@64(32).
#define RREC 100
#define F_DY 0
#define F_H  16
#define F_Q  48
#define F_DH 64
#define WAVE_HALFS (32*RREC)              // 6.4 KB / wave
#define K1_SMEM_BYTES 28672               // max(staging 25.6KB, reduction 28.7KB)

// k3 per-row record: qhi@0(16) | qlo@16(16) | hhi@32(32) | hlo@64(32)
#define R3 100
#define Q_HI 0
#define Q_LO 16
#define H_HI 32
#define H_LO 64

#if __has_builtin(__builtin_amdgcn_rcpf)
#define RCPF(x) __builtin_amdgcn_rcpf(x)
#else
#define RCPF(x) (1.f/(x))
#endif
#if __has_builtin(__builtin_amdgcn_rsqf)
#define RSQF(x) __builtin_amdgcn_rsqf(x)
#else
#define RSQF(x) (1.f/sqrtf(x))
#endif

__device__ __forceinline__ float sigmoidf_(float z){ return RCPF(1.f + __expf(-z)); }

__device__ __forceinline__ unsigned pk2_(float a, float b){
  union { __bf16 h[2]; unsigned u; } x; x.h[0]=(__bf16)a; x.h[1]=(__bf16)b; return x.u;
}
__device__ __forceinline__ float upks_(unsigned u, int s){
  return s ? __uint_as_float(u & 0xffff0000u) : __uint_as_float(u << 16);
}
__device__ __forceinline__ void splitpk_(float a, float b, unsigned &uh, unsigned &ul){
  unsigned h = pk2_(a,b);
  float ah = __uint_as_float(h << 16);
  float bh = __uint_as_float(h & 0xffff0000u);
  uh = h; ul = pk2_(a - ah, b - bh);
}
__device__ __forceinline__ void load_split8_(const float* p, U8 &H, U8 &L){
  const float4 u0 = *(const float4*)p;
  const float4 u1 = *(const float4*)(p+4);
  splitpk_(u0.x,u0.y,H.u[0],L.u[0]); splitpk_(u0.z,u0.w,H.u[1],L.u[1]);
  splitpk_(u1.x,u1.y,H.u[2],L.u[2]); splitpk_(u1.z,u1.w,H.u[3],L.u[3]);
}
__device__ __forceinline__ void pack8f_(const float* p, U8 &A){
  const float4 u0 = *(const float4*)p;
  const float4 u1 = *(const float4*)(p+4);
  A.u[0]=pk2_(u0.x,u0.y); A.u[1]=pk2_(u0.z,u0.w); A.u[2]=pk2_(u1.x,u1.y); A.u[3]=pk2_(u1.z,u1.w);
}

// ---------------- Kernel 1: gradient pass (R13/R14 proven 55.5us config) ----------------
__global__ __launch_bounds__(256, 3)
void k1_grad(const float* __restrict__ X,
             const float* __restrict__ W0, const float* __restrict__ b0,
             const float* __restrict__ W1, const float* __restrict__ b1,
             const float* __restrict__ WV, const float* __restrict__ WQ,
             float* __restrict__ wsPart, int N)
{
  __shared__ __align__(16) unsigned char smem_raw[K1_SMEM_BYTES];
  const int tid = threadIdx.x;
  const int w = tid >> 6, l = tid & 63;
  const int row = l & 31, hi = l >> 5;
  const int c16 = l & 15, g16 = l >> 4;
  __bf16* WB = (__bf16*)smem_raw + w*WAVE_HALFS;

  bf16x8 ones;
  #pragma unroll
  for (int i=0;i<8;++i) ones[i] = (__bf16)1.f;

  U8 aWVQ, aW0p;
  pack8f_((row < 16) ? (WV + row*16 + hi*8) : (WQ + (row-16)*16 + hi*8), aWVQ);
  pack8f_(W0 + row*16 + hi*8, aW0p);

  f32x4 accW[4] = {};
  f32x4 accB1 = {}, accB0a = {}, accB0b = {};

  const int nb = N >> 6;
  const int tw = K1_BLOCKS*4;
  const int gw = blockIdx.x*4 + w;
  const int iters = (nb + tw - 1) / tw;

  for (int it = 0; it < iters; ++it) {
    const int batch = gw + it*tw;
    if (batch < nb) {
      const float* xb = X + (size_t)batch*1024;

      #pragma unroll
      for (int hf=0; hf<2; ++hf){
        const float* xh = xb + hf*512;
        __bf16* R = WB + row*RREC;

        // ---- phase 1: one MFMA -> v (rows 0-15) and q-pre (rows 16-31) ----
        U8 bX; pack8f_(xh + row*16 + hi*8, bX);
        f32x16 c1;
        #pragma unroll
        for (int i=0;i<16;++i) c1[i] = 0.f;
        c1 = __builtin_amdgcn_mfma_f32_32x32x16_bf16(aWVQ.v, bX.v, c1, 0,0,0);
        unsigned vvp[4];
        #pragma unroll
        for (int j=0;j<4;++j){
          float a = c1[2*j],  sa = a*sigmoidf_(a);
          float b = c1[2*j+1],sb = b*sigmoidf_(b);
          vvp[j] = pk2_(sa, sb);
        }
        float qv[8]; float n2 = 0.f;
        #pragma unroll
        for (int r=0;r<8;++r){
          float s = c1[8+r]; float t = s*sigmoidf_(s);
          qv[r] = t; n2 = fmaf(t,t,n2);
        }
        n2 += __shfl_xor(n2, 32);
        const float inv = RSQF(fmaxf(n2, 1e-24f));
        *(uint2*)(R + F_Q + 4*hi)     = make_uint2(pk2_(qv[0]*inv,qv[1]*inv), pk2_(qv[2]*inv,qv[3]*inv));
        *(uint2*)(R + F_Q + 8 + 4*hi) = make_uint2(pk2_(qv[4]*inv,qv[5]*inv), pk2_(qv[6]*inv,qv[7]*inv));

        // ---- phase 2: h = silu(W0 q^T + b0), one MFMA ----
        U8 bq;
        { const __bf16* p = R + F_Q + hi*8;
          bq.d[0] = *(const uint2*)p; bq.d[1] = *(const uint2*)(p+4); }
        f32x16 c2;
        { const float4 bA = *(const float4*)(b0 + 4*hi);
          const float4 bB = *(const float4*)(b0 + 8 + 4*hi);
          const float4 bC = *(const float4*)(b0 + 16 + 4*hi);
          const float4 bD = *(const float4*)(b0 + 24 + 4*hi);
          c2[0]=bA.x;c2[1]=bA.y;c2[2]=bA.z;c2[3]=bA.w;
          c2[4]=bB.x;c2[5]=bB.y;c2[6]=bB.z;c2[7]=bB.w;
          c2[8]=bC.x;c2[9]=bC.y;c2[10]=bC.z;c2[11]=bC.w;
          c2[12]=bD.x;c2[13]=bD.y;c2[14]=bD.z;c2[15]=bD.w; }
        c2 = __builtin_amdgcn_mfma_f32_32x32x16_bf16(aW0p.v, bq.v, c2, 0,0,0);
        unsigned hpk[8], dshp[8];
        #pragma unroll
        for (int j=0;j<8;++j){
          float sa = c2[2*j],   sga = sigmoidf_(sa);
          float sb = c2[2*j+1], sgb = sigmoidf_(sb);
          hpk[j]  = pk2_(sa*sga, sb*sgb);
          dshp[j] = pk2_(sga*fmaf(sa,1.f-sga,1.f), sgb*fmaf(sb,1.f-sgb,1.f));
        }
        *(uint2*)(R + F_H + 4*hi)      = make_uint2(hpk[0],hpk[1]);
        *(uint2*)(R + F_H + 8 + 4*hi)  = make_uint2(hpk[2],hpk[3]);
        *(uint2*)(R + F_H + 16 + 4*hi) = make_uint2(hpk[4],hpk[5]);
        *(uint2*)(R + F_H + 24 + 4*hi) = make_uint2(hpk[6],hpk[7]);

        // ---- phase 3: y = silu(W1 h^T + b1); dy -> F_DY ----
        U8 a1, a2;
        #pragma unroll
        for (int i=0;i<4;++i){ a1.u[i]=0; a2.u[i]=0; }
        if (row < 16) pack8f_(W1 + row*32 + hi*8, a1);
        else          pack8f_(W1 + (row-16)*32 + 16 + hi*8, a2);
        U8 bhlo, bhhi;
        { const __bf16* p = R + F_H + hi*8;
          bhlo.d[0] = *(const uint2*)p; bhlo.d[1] = *(const uint2*)(p+4);
          const __bf16* p2 = R + F_H + 16 + hi*8;
          bhhi.d[0] = *(const uint2*)p2; bhhi.d[1] = *(const uint2*)(p2+4); }
        f32x16 c3;
        { const float4 bA = *(const float4*)(b1 + 4*hi);
          const float4 bB = *(const float4*)(b1 + 8 + 4*hi);
          c3[0]=bA.x;c3[1]=bA.y;c3[2]=bA.z;c3[3]=bA.w;
          c3[4]=bB.x;c3[5]=bB.y;c3[6]=bB.z;c3[7]=bB.w;
          #pragma unroll
          for (int i=8;i<16;++i) c3[i]=0.f; }
        c3 = __builtin_amdgcn_mfma_f32_32x32x16_bf16(a1.v, bhlo.v, c3, 0,0,0);
        c3 = __builtin_amdgcn_mfma_f32_32x32x16_bf16(a2.v, bhhi.v, c3, 0,0,0);
        unsigned dypk[4];
        #pragma unroll
        for (int j=0;j<4;++j){
          float d2[2];
          #pragma unroll
          for (int e=0;e<2;++e){
            int r = 2*j+e;
            float s = c3[r] + c3[r+8];
            float sg = sigmoidf_(s);
            float y = s*sg;
            float ds = sg * fmaf(s, 1.f - sg, 1.f);
            d2[e] = (y - upks_(vvp[r>>1], r&1)) * ds;
          }
          dypk[j] = pk2_(d2[0], d2[1]);
        }
        *(uint2*)(R + F_DY + 4*hi)     = make_uint2(dypk[0],dypk[1]);
        *(uint2*)(R + F_DY + 8 + 4*hi) = make_uint2(dypk[2],dypk[3]);

        // ---- phase 4: dh = (W1^T dy^T) * dsilu -> F_DH, one MFMA ----
        U8 aT;
        { float t0 = W1[(hi*8+0)*32 + row], t1 = W1[(hi*8+1)*32 + row];
          float t2 = W1[(hi*8+2)*32 + row], t3 = W1[(hi*8+3)*32 + row];
          float t4 = W1[(hi*8+4)*32 + row], t5 = W1[(hi*8+5)*32 + row];
          float t6 = W1[(hi*8+6)*32 + row], t7 = W1[(hi*8+7)*32 + row];
          aT.u[0]=pk2_(t0,t1); aT.u[1]=pk2_(t2,t3); aT.u[2]=pk2_(t4,t5); aT.u[3]=pk2_(t6,t7); }
        U8 bdy;
        { const __bf16* p = R + F_DY + hi*8;
          bdy.d[0] = *(const uint2*)p; bdy.d[1] = *(const uint2*)(p+4); }
        f32x16 c4;
        #pragma unroll
        for (int i=0;i<16;++i) c4[i]=0.f;
        c4 = __builtin_amdgcn_mfma_f32_32x32x16_bf16(aT.v, bdy.v, c4, 0,0,0);
        unsigned dhpk[8];
        #pragma unroll
        for (int j=0;j<8;++j){
          float d0 = c4[2*j]   * upks_(dshp[j],0);
          float d1 = c4[2*j+1] * upks_(dshp[j],1);
          dhpk[j] = pk2_(d0,d1);
        }
        *(uint2*)(R + F_DH + 4*hi)      = make_uint2(dhpk[0],dhpk[1]);
        *(uint2*)(R + F_DH + 8 + 4*hi)  = make_uint2(dhpk[2],dhpk[3]);
        *(uint2*)(R + F_DH + 16 + 4*hi) = make_uint2(dhpk[4],dhpk[5]);
        *(uint2*)(R + F_DH + 24 + 4*hi) = make_uint2(dhpk[6],dhpk[7]);

        // ---- gradient MFMAs (16x16x32, proven path) ----
        const __bf16* gbase = WB + (g16*8)*RREC + c16;
        {
          bf16x8 fdy, fh0, fh1;
          #pragma unroll
          for (int i=0;i<8;++i){
            const __bf16* pr = gbase + i*RREC;
            fdy[i] = pr[F_DY];
            fh0[i] = pr[F_H];
            fh1[i] = pr[F_H + 16];
          }
          accW[0] = __builtin_amdgcn_mfma_f32_16x16x32_bf16(fdy, fh0, accW[0], 0,0,0);
          accW[1] = __builtin_amdgcn_mfma_f32_16x16x32_bf16(fdy, fh1, accW[1], 0,0,0);
          accB1   = __builtin_amdgcn_mfma_f32_16x16x32_bf16(fdy, ones, accB1, 0,0,0);
        }
        {
          bf16x8 fd0, fd1, fq;
          #pragma unroll
          for (int i=0;i<8;++i){
            const __bf16* pr = gbase + i*RREC;
            fd0[i] = pr[F_DH];
            fd1[i] = pr[F_DH + 16];
            fq[i]  = pr[F_Q];
          }
          accW[2] = __builtin_amdgcn_mfma_f32_16x16x32_bf16(fd0, fq, accW[2], 0,0,0);
          accW[3] = __builtin_amdgcn_mfma_f32_16x16x32_bf16(fd1, fq, accW[3], 0,0,0);
          accB0a  = __builtin_amdgcn_mfma_f32_16x16x32_bf16(fd0, ones, accB0a, 0,0,0);
          accB0b  = __builtin_amdgcn_mfma_f32_16x16x32_bf16(fd1, ones, accB0b, 0,0,0);
        }
      }
    }
  }

  __syncthreads();
  float* red = (float*)smem_raw;
  #pragma unroll
  for (int r=0;r<4;++r){
    red[w*1792 + 0*256 + l*4 + r] = accW[0][r];
    red[w*1792 + 1*256 + l*4 + r] = accW[1][r];
    red[w*1792 + 2*256 + l*4 + r] = accB1[r];
    red[w*1792 + 3*256 + l*4 + r] = accW[2][r];
    red[w*1792 + 4*256 + l*4 + r] = accW[3][r];
    red[w*1792 + 5*256 + l*4 + r] = accB0a[r];
    red[w*1792 + 6*256 + l*4 + r] = accB0b[r];
  }
  __syncthreads();
  for (int s = tid; s < 1792; s += 256){
    float sum = red[s] + red[1792+s] + red[2*1792+s] + red[3*1792+s];
    wsPart[(size_t)blockIdx.x*1792 + s] = sum;
  }
}

// ---------------- Kernel 2 (fused): reduce 1536 partials + form updated params ----------------
// Grid 28 x 1024. Thread (sl = tid&63, c = tid>>6) sums its 96-partial chunk
// (wave reads are 64 consecutive s -> 256B coalesced); 4KB LDS collapses the
// 16 chunks; lanes tid<64 apply the R10-mapping parameter update. Replaces
// k2a+k2b (one launch + the 115KB tmp round-trip saved).
__global__ __launch_bounds__(1024)
void k2_fused(const float* __restrict__ wsPart,
              const float* __restrict__ W0, const float* __restrict__ b0,
              const float* __restrict__ W1, const float* __restrict__ b1,
              float* __restrict__ P, float scale)
{
  __shared__ float red[16*64];
  const int tid = threadIdx.x;
  const int sl = tid & 63, c = tid >> 6;       // c in 0..15
  const int s = blockIdx.x*64 + sl;            // 28*64 = 1792 exactly

  float g = 0.f;
  const float* base = wsPart + (size_t)(c*(K1_BLOCKS/16))*1792 + s;
  #pragma unroll 8
  for (int j=0;j<K1_BLOCKS/16;++j) g += base[(size_t)j*1792];
  red[c*64 + sl] = g;
  __syncthreads();

  if (tid < 64){
    float gg = 0.f;
    #pragma unroll
    for (int cc=0;cc<16;++cc) gg += red[cc*64 + tid];
    gg *= scale;
    const int ss = blockIdx.x*64 + tid;
    int a = ss >> 8, l = (ss >> 2) & 63, r = ss & 3;
    int m = ((l>>4)<<2) + r, n = l & 15;
    if (a==0)      P[544 + m*32 + n]       = ALPHA*W1[m*32+n]        - THETA*gg;
    else if (a==1) P[544 + m*32 + 16 + n]  = ALPHA*W1[m*32+16+n]     - THETA*gg;
    else if (a==2){ if (n==0) P[1056 + m]  = ALPHA*b1[m]             - THETA*gg; }
    else if (a==3) P[m*16 + n]             = ALPHA*W0[m*16+n]        - THETA*gg;
    else if (a==4) P[(16+m)*16 + n]        = ALPHA*W0[(16+m)*16+n]   - THETA*gg;
    else if (a==5){ if (n==0) P[512 + m]   = ALPHA*b0[m]             - THETA*gg; }
    else           { if (n==0) P[512+16+m] = ALPHA*b0[16+m]          - THETA*gg; }
  }
}

// ---------------- Kernel 3: retrieve, 32x32x16 MFMA with [Wh;Wl] A-packing (R14) ----------------
__global__ __launch_bounds__(256, 3)
void k3_retrieve(const float* __restrict__ X, const float* __restrict__ WQ,
                 const float* __restrict__ P, float* __restrict__ out, int N)
{
  __shared__ __align__(16) __bf16 smem[4*32*R3];   // 25600 B
  const int tid = threadIdx.x;
  const int w = tid >> 6, l = tid & 63;
  const int col = l & 31, hi = l >> 5;
  __bf16* WB = smem + w*32*R3;
  __bf16* R = WB + col*R3;

  // A-frags
  U8 aQ, aW0h_, aW0l_, a1, a2;
  {
    U8 Hh, Ll;
    load_split8_(WQ + (col & 15)*16 + hi*8, Hh, Ll);
    aQ = (col < 16) ? Hh : Ll;                       // [WQh; WQl]
    load_split8_(P + col*16 + hi*8, aW0h_, aW0l_);   // W0' 32 rows native
    load_split8_(P + 544 + (col & 15)*32 + hi*8, Hh, Ll);
    a1 = (col < 16) ? Hh : Ll;                       // [W1h; W1l], k 0-15
    load_split8_(P + 544 + (col & 15)*32 + 16 + hi*8, Hh, Ll);
    a2 = (col < 16) ? Hh : Ll;                       // [W1h; W1l], k 16-31
  }

  const int nb = N >> 6;
  const int tw = K3_BLOCKS*4;
  const int gw = blockIdx.x*4 + w;
  const int iters = (nb + tw - 1) / tw;

  for (int it=0; it<iters; ++it){
    const int batch = gw + it*tw;
    if (batch < nb){
      #pragma unroll
      for (int sb=0; sb<2; ++sb){
        const float* xs = X + (size_t)batch*1024 + sb*512;

        // ---- phase 1: s = WQ x^T (exact); q = silu(l2norm(s)) hi/lo -> LDS ----
        U8 bXh, bXl;
        load_split8_(xs + col*16 + hi*8, bXh, bXl);
        f32x16 c1;
        #pragma unroll
        for (int i=0;i<16;++i) c1[i]=0.f;
        c1 = __builtin_amdgcn_mfma_f32_32x32x16_bf16(aQ.v, bXh.v, c1, 0,0,0);
        c1 = __builtin_amdgcn_mfma_f32_32x32x16_bf16(aQ.v, bXl.v, c1, 0,0,0);
        float sv[8]; float n2 = 0.f;
        #pragma unroll
        for (int r=0;r<8;++r){ sv[r] = c1[r] + c1[r+8]; n2 = fmaf(sv[r],sv[r],n2); }
        n2 += __shfl_xor(n2, 32);
        const float inv = RSQF(fmaxf(n2, 1e-24f));
        unsigned qh[4], ql[4];
        #pragma unroll
        for (int j=0;j<4;++j){
          float z0 = sv[2*j]*inv,   z1 = sv[2*j+1]*inv;
          float q0 = z0*sigmoidf_(z0), q1 = z1*sigmoidf_(z1);
          splitpk_(q0,q1,qh[j],ql[j]);
        }
        *(uint2*)(R + Q_HI + 4*hi)     = make_uint2(qh[0],qh[1]);
        *(uint2*)(R + Q_HI + 8 + 4*hi) = make_uint2(qh[2],qh[3]);
        *(uint2*)(R + Q_LO + 4*hi)     = make_uint2(ql[0],ql[1]);
        *(uint2*)(R + Q_LO + 8 + 4*hi) = make_uint2(ql[2],ql[3]);

        // ---- phase 2: h = silu(W0' q^T + b0') hi/lo -> LDS ----
        U8 bqh, bql;
        { const __bf16* p = R + Q_HI + hi*8;
          bqh.d[0]=*(const uint2*)p; bqh.d[1]=*(const uint2*)(p+4);
          const __bf16* p2 = R + Q_LO + hi*8;
          bql.d[0]=*(const uint2*)p2; bql.d[1]=*(const uint2*)(p2+4); }
        f32x16 c2;
        { const float4 bA = *(const float4*)(P + 512 + 4*hi);
          const float4 bB = *(const float4*)(P + 512 + 8 + 4*hi);
          const float4 bC = *(const float4*)(P + 512 + 16 + 4*hi);
          const float4 bD = *(const float4*)(P + 512 + 24 + 4*hi);
          c2[0]=bA.x;c2[1]=bA.y;c2[2]=bA.z;c2[3]=bA.w;
          c2[4]=bB.x;c2[5]=bB.y;c2[6]=bB.z;c2[7]=bB.w;
          c2[8]=bC.x;c2[9]=bC.y;c2[10]=bC.z;c2[11]=bC.w;
          c2[12]=bD.x;c2[13]=bD.y;c2[14]=bD.z;c2[15]=bD.w; }
        c2 = __builtin_amdgcn_mfma_f32_32x32x16_bf16(aW0h_.v, bqh.v, c2, 0,0,0);
        c2 = __builtin_amdgcn_mfma_f32_32x32x16_bf16(aW0h_.v, bql.v, c2, 0,0,0);
        c2 = __builtin_amdgcn_mfma_f32_32x32x16_bf16(aW0l_.v, bqh.v, c2, 0,0,0);
        unsigned hh[8], hl[8];
        #pragma unroll
        for (int j=0;j<8;++j){
          float s0 = c2[2*j], s1 = c2[2*j+1];
          float h0 = s0*sigmoidf_(s0), h1 = s1*sigmoidf_(s1);
          splitpk_(h0,h1,hh[j],hl[j]);
        }
        *(uint2*)(R + H_HI + 4*hi)      = make_uint2(hh[0],hh[1]);
        *(uint2*)(R + H_HI + 8 + 4*hi)  = make_uint2(hh[2],hh[3]);
        *(uint2*)(R + H_HI + 16 + 4*hi) = make_uint2(hh[4],hh[5]);
        *(uint2*)(R + H_HI + 24 + 4*hi) = make_uint2(hh[6],hh[7]);
        *(uint2*)(R + H_LO + 4*hi)      = make_uint2(hl[0],hl[1]);
        *(uint2*)(R + H_LO + 8 + 4*hi)  = make_uint2(hl[2],hl[3]);
        *(uint2*)(R + H_LO + 16 + 4*hi) = make_uint2(hl[4],hl[5]);
        *(uint2*)(R + H_LO + 24 + 4*hi) = make_uint2(hl[6],hl[7]);

        // ---- phase 3: o = silu(W1' h^T + b1'), coalesced float4 writes ----
        U8 bhh0, bhh1, bhl0, bhl1;
        { const __bf16* p;
          p = R + H_HI + hi*8;      bhh0.d[0]=*(const uint2*)p; bhh0.d[1]=*(const uint2*)(p+4);
          p = R + H_HI + 16 + hi*8; bhh1.d[0]=*(const uint2*)p; bhh1.d[1]=*(const uint2*)(p+4);
          p = R + H_LO + hi*8;      bhl0.d[0]=*(const uint2*)p; bhl0.d[1]=*(const uint2*)(p+4);
          p = R + H_LO + 16 + hi*8; bhl1.d[0]=*(const uint2*)p; bhl1.d[1]=*(const uint2*)(p+4); }
        f32x16 c3;
        { const float4 bA = *(const float4*)(P + 1056 + 4*hi);
          const float4 bB = *(const float4*)(P + 1056 + 8 + 4*hi);
          c3[0]=bA.x;c3[1]=bA.y;c3[2]=bA.z;c3[3]=bA.w;
          c3[4]=bB.x;c3[5]=bB.y;c3[6]=bB.z;c3[7]=bB.w;
          #pragma unroll
          for (int i=8;i<16;++i) c3[i]=0.f; }
        c3 = __builtin_amdgcn_mfma_f32_32x32x16_bf16(a1.v, bhh0.v, c3, 0,0,0);
        c3 = __builtin_amdgcn_mfma_f32_32x32x16_bf16(a2.v, bhh1.v, c3, 0,0,0);
        c3 = __builtin_amdgcn_mfma_f32_32x32x16_bf16(a1.v, bhl0.v, c3, 0,0,0);
        c3 = __builtin_amdgcn_mfma_f32_32x32x16_bf16(a2.v, bhl1.v, c3, 0,0,0);
        float oo[8];
        #pragma unroll
        for (int r=0;r<8;++r){
          float s = c3[r] + c3[r+8];
          oo[r] = s * sigmoidf_(s);
        }
        const size_t xrow = (size_t)batch*64 + sb*32 + col;
        *(float4*)(out + xrow*16 + 4*hi)     = make_float4(oo[0],oo[1],oo[2],oo[3]);
        *(float4*)(out + xrow*16 + 8 + 4*hi) = make_float4(oo[4],oo[5],oo[6],oo[7]);
      }
    }
  }
}

extern "C" void kernel_launch(void* const* d_in, const int* in_sizes, int n_in,
                              void* d_out, int out_size, void* d_ws, size_t ws_size,
                              hipStream_t stream)
{
  const float* X  = (const float*)d_in[0];
  const float* W0 = (const float*)d_in[1];
  const float* b0 = (const float*)d_in[2];
  const float* W1 = (const float*)d_in[3];
  const float* b1 = (const float*)d_in[4];
  const float* WV = (const float*)d_in[6];
  const float* WQ = (const float*)d_in[7];
  float* ws   = (float*)d_ws;
  float* P    = ws;                         // 1072 floats of updated params
  float* part = ws + 2048;                  // 1536*1792 floats of partials

  const int N = in_sizes[0] / 16;
  const float scale = 2.f / (16.f * (float)N);

  k1_grad<<<dim3(K1_BLOCKS), dim3(256), 0, stream>>>(X, W0, b0, W1, b1, WV, WQ, part, N);
  k2_fused<<<dim3(28), dim3(1024), 0, stream>>>(part, W0, b0, W1, b1, P, scale);
  k3_retrieve<<<dim3(K3_BLOCKS), dim3(256), 0, stream>>>(X, WQ, P, (float*)d_out, N);
}